// Round 1
// baseline (3567.078 us; speedup 1.0000x reference)
//
#include <hip/hip_runtime.h>
#include <hip/hip_bf16.h>

#define B_ 128
#define T_ 256
#define DV 512
#define H_ 1024
#define C_ 512

typedef _Float16 half8 __attribute__((ext_vector_type(8)));
typedef float f32x4 __attribute__((ext_vector_type(4)));

__device__ __forceinline__ float sigmoidf_(float x){ return 1.f/(1.f+__expf(-x)); }
__device__ __forceinline__ float tanhf_(float x){
  x = fminf(12.f, fmaxf(-12.f, x));
  float e = __expf(2.f*x);
  return (e-1.f)/(e+1.f);
}
__device__ __forceinline__ f32x4 mfma16(half8 a, half8 b, f32x4 c){
  return __builtin_amdgcn_mfma_f32_16x16x32_f16(a, b, c, 0, 0, 0);
}

// ---------------- pre-kernels ----------------

// x [B][T] -> xT [T][B]
__global__ void k_transpose_x(const int* __restrict__ x, int* __restrict__ xT){
  int idx = blockIdx.x*256 + threadIdx.x;
  int t = idx >> 7, b = idx & 127;
  xT[idx] = x[b*T_ + t];
}

// PT_g[token][h] = sum_d W_g[h][d] * embed[token][d]   (fp32, exact path)
__global__ __launch_bounds__(256) void k_compute_PT(
    const float* __restrict__ embed,
    const float* __restrict__ Wz, const float* __restrict__ Wr, const float* __restrict__ Wh,
    float* __restrict__ PT){
  const float* Wg = (blockIdx.z==0)?Wz:((blockIdx.z==1)?Wr:Wh);
  float* P = PT + (size_t)blockIdx.z*DV*H_;
  __shared__ float Et[64][17];
  __shared__ float Wt[64][17];
  int tid = threadIdx.x;
  int tok0 = blockIdx.x*64, h0 = blockIdx.y*64;
  int ty = tid>>4, tx = tid&15;
  float acc[4][4];
  #pragma unroll
  for(int i=0;i<4;i++)
    #pragma unroll
    for(int j=0;j<4;j++) acc[i][j]=0.f;
  for(int d0=0; d0<DV; d0+=16){
    __syncthreads();
    for(int i=tid;i<64*16;i+=256){
      int r=i>>4, c=i&15;
      Et[r][c] = embed[(tok0+r)*DV + d0 + c];
      Wt[r][c] = Wg[(h0+r)*DV + d0 + c];
    }
    __syncthreads();
    #pragma unroll
    for(int d=0; d<16; d++){
      float av[4], bv[4];
      #pragma unroll
      for(int i=0;i<4;i++) av[i]=Et[ty*4+i][d];
      #pragma unroll
      for(int j=0;j<4;j++) bv[j]=Wt[tx*4+j][d];
      #pragma unroll
      for(int i=0;i<4;i++)
        #pragma unroll
        for(int j=0;j<4;j++) acc[i][j] += av[i]*bv[j];
    }
  }
  #pragma unroll
  for(int i=0;i<4;i++)
    #pragma unroll
    for(int j=0;j<4;j++)
      P[(size_t)(tok0+ty*4+i)*H_ + h0 + tx*4 + j] = acc[i][j];
}

// U (fp32 [H][H]) -> fragment-major fp16: Ufrag[((g*64+rt)*32+kc)*64+lane][e]
// slot (lane,e) holds U[rt*16 + (lane&15)][kc*32 + 16*(e>>2) + 4*(lane>>4) + (e&3)]
__global__ __launch_bounds__(256) void k_build_Ufrag(
    const float* __restrict__ Uz, const float* __restrict__ Ur, const float* __restrict__ Uh,
    half8* __restrict__ Ufrag){
  int idx = blockIdx.x*256 + threadIdx.x;
  int l  = idx & 63;
  int kc = (idx>>6) & 31;
  int rt = (idx>>11) & 63;
  int g  = idx>>17;
  const float* Ug = (g==0)?Uz:((g==1)?Ur:Uh);
  int row = rt*16 + (l&15);
  int kb  = kc*32 + 4*(l>>4);
  f32x4 lo = *(const f32x4*)(Ug + (size_t)row*H_ + kb);
  f32x4 hi = *(const f32x4*)(Ug + (size_t)row*H_ + kb + 16);
  half8 o;
  o[0]=(_Float16)lo[0]; o[1]=(_Float16)lo[1]; o[2]=(_Float16)lo[2]; o[3]=(_Float16)lo[3];
  o[4]=(_Float16)hi[0]; o[5]=(_Float16)hi[1]; o[6]=(_Float16)hi[2]; o[7]=(_Float16)hi[3];
  Ufrag[idx] = o;
}

// ---------------- recurrent step ----------------
// grid dim3(32,2), block 256. wave w handles rows [32*rp, 32*rp+32) x cols [16*ct, 16*ct+16)
// h stored fragment-major: h[kc][ct][lane][e], one half8 per lane.
__global__ __launch_bounds__(256,1) void k_step(
    int t,
    const half8* __restrict__ hin,
    half8* __restrict__ hout,
    const half8* __restrict__ Ufrag,
    const float* __restrict__ PTz, const float* __restrict__ PTr, const float* __restrict__ PTh,
    const int* __restrict__ xT){
  int tid  = threadIdx.x;
  int lane = tid & 63;
  int w    = tid >> 6;
  int rp   = blockIdx.x;            // row-pair: rows [32rp, 32rp+32)
  int ct   = blockIdx.y*4 + w;      // col tile: cols [16ct, 16ct+16)
  int rt0  = rp*2;

  f32x4 az0={0,0,0,0}, az1={0,0,0,0};
  f32x4 ar0={0,0,0,0}, ar1={0,0,0,0};
  f32x4 ah0={0,0,0,0}, ah1={0,0,0,0};
  half8 hold = {};

  #pragma unroll 4
  for(int kc=0; kc<32; ++kc){
    half8 b = hin[(kc*8 + ct)*64 + lane];
    half8 a;
    a = Ufrag[(((0*64 + rt0  )*32 + kc)<<6) + lane]; az0 = mfma16(a,b,az0);
    a = Ufrag[(((0*64 + rt0+1)*32 + kc)<<6) + lane]; az1 = mfma16(a,b,az1);
    a = Ufrag[(((1*64 + rt0  )*32 + kc)<<6) + lane]; ar0 = mfma16(a,b,ar0);
    a = Ufrag[(((1*64 + rt0+1)*32 + kc)<<6) + lane]; ar1 = mfma16(a,b,ar1);
    a = Ufrag[(((2*64 + rt0  )*32 + kc)<<6) + lane]; ah0 = mfma16(a,b,ah0);
    a = Ufrag[(((2*64 + rt0+1)*32 + kc)<<6) + lane]; ah1 = mfma16(a,b,ah1);
    if(kc == rp) hold = b;   // own k-chunk == h_old for our rows/cols, same lane mapping
  }

  int col   = ct*16 + (lane&15);
  int token = xT[t*B_ + col];
  int q     = lane>>4;
  half8 ho;
  #pragma unroll
  for(int tl=0; tl<2; ++tl){
    int rowq = rp*32 + tl*16 + 4*q;
    f32x4 pz = *(const f32x4*)(PTz + (size_t)token*H_ + rowq);
    f32x4 pr = *(const f32x4*)(PTr + (size_t)token*H_ + rowq);
    f32x4 ph = *(const f32x4*)(PTh + (size_t)token*H_ + rowq);
    f32x4 vz = tl ? az1 : az0;
    f32x4 vr = tl ? ar1 : ar0;
    f32x4 vh = tl ? ah1 : ah0;
    #pragma unroll
    for(int r=0;r<4;++r){
      float z  = sigmoidf_(pz[r] + vz[r]);
      float rr = sigmoidf_(pr[r] + vr[r]);
      float hh = tanhf_(ph[r] + rr*vh[r]);
      float hp = (float)hold[tl*4+r];
      float hn = tanhf_(z*hp + (1.f-z)*hh);
      ho[tl*4+r] = (_Float16)hn;
    }
  }
  hout[(rp*8 + ct)*64 + lane] = ho;
}

// ---------------- epilogue ----------------

__global__ void k_unfrag(const _Float16* __restrict__ hf, float* __restrict__ hlin){
  int idx = blockIdx.x*256 + threadIdx.x;  // idx = i*128 + b
  int b = idx & 127, i = idx >> 7;
  int kc = i>>5, kr = i&31;
  int l = ((kr>>2)&3)*16 + (b&15);
  int e = (kr>>4)*4 + (kr&3);
  int ct = b>>4;
  hlin[idx] = (float)hf[(((kc*8+ct)*64 + l)<<3) + e];
}

// yT[b][c] = sum_i Wph[c][i]*h[i][b] + bp[c]
__global__ __launch_bounds__(256) void k_out_gemm(
    const float* __restrict__ hlin, const float* __restrict__ Wph,
    const float* __restrict__ bp, float* __restrict__ yT){
  __shared__ float hs[64][128];
  int tid = threadIdx.x;
  int c0 = blockIdx.x*16;
  int cl = tid>>4, bg = tid&15;
  float acc[8] = {0,0,0,0,0,0,0,0};
  for(int i0=0;i0<H_;i0+=64){
    __syncthreads();
    for(int i=tid;i<64*128;i+=256){
      int r=i>>7, b=i&127;
      hs[r][b] = hlin[(i0+r)*B_ + b];
    }
    __syncthreads();
    for(int il=0; il<64; ++il){
      float wv = Wph[(size_t)(c0+cl)*H_ + i0 + il];
      const float* hrow = &hs[il][bg*8];
      #pragma unroll
      for(int j=0;j<8;++j) acc[j] += wv * hrow[j];
    }
  }
  float bias = bp[c0+cl];
  #pragma unroll
  for(int j=0;j<8;++j){
    int b = bg*8+j;
    yT[(size_t)b*C_ + c0+cl] = acc[j] + bias;
  }
}

__global__ __launch_bounds__(256) void k_logsoftmax(const float* __restrict__ yT, float* __restrict__ out){
  __shared__ float red[256];
  int b = blockIdx.x, tid = threadIdx.x;
  float v0 = yT[(size_t)b*C_ + tid];
  float v1 = yT[(size_t)b*C_ + 256 + tid];
  red[tid] = fmaxf(v0,v1); __syncthreads();
  for(int s=128;s>0;s>>=1){ if(tid<s) red[tid]=fmaxf(red[tid],red[tid+s]); __syncthreads(); }
  float M = red[0]; __syncthreads();
  red[tid] = __expf(v0-M)+__expf(v1-M); __syncthreads();
  for(int s=128;s>0;s>>=1){ if(tid<s) red[tid]+=red[tid+s]; __syncthreads(); }
  float L = M + logf(red[0]);
  out[(size_t)b*C_ + tid]       = v0 - L;
  out[(size_t)b*C_ + 256 + tid] = v1 - L;
}

// ---------------- launcher ----------------

extern "C" void kernel_launch(void* const* d_in, const int* in_sizes, int n_in,
                              void* d_out, int out_size, void* d_ws, size_t ws_size,
                              hipStream_t stream){
  const int*   x    = (const int*)  d_in[0];
  const float* embed= (const float*)d_in[1];
  const float* Wz   = (const float*)d_in[2];
  const float* Uz   = (const float*)d_in[3];
  const float* Wr   = (const float*)d_in[4];
  const float* Ur   = (const float*)d_in[5];
  const float* Wh   = (const float*)d_in[6];
  const float* Uh   = (const float*)d_in[7];
  const float* Wph  = (const float*)d_in[8];
  const float* bp   = (const float*)d_in[9];
  float* out = (float*)d_out;

  char* w = (char*)d_ws;
  float*    PT    = (float*)(w);                                // 6 MB (3 x 512x1024 f32)
  half8*    Ufrag = (half8*)(w + (6u<<20));                      // 6 MB fp16 frags
  _Float16* hbuf0 = (_Float16*)(w + (12u<<20));                  // 256 KB
  _Float16* hbuf1 = (_Float16*)(w + (12u<<20) + (256u<<10));     // 256 KB
  int*      xT    = (int*)(w + (12u<<20) + (512u<<10));          // 128 KB
  float*    hlin  = (float*)(w + (12u<<20) + (640u<<10));        // 512 KB
  float*    yT    = (float*)(w + (12u<<20) + (1152u<<10));       // 256 KB

  k_transpose_x<<<128,256,0,stream>>>(x, xT);
  k_compute_PT<<<dim3(8,16,3),256,0,stream>>>(embed, Wz, Wr, Wh, PT);
  k_build_Ufrag<<<1536,256,0,stream>>>(Uz, Ur, Uh, Ufrag);
  hipMemsetAsync(hbuf0, 0, 256u<<10, stream);

  _Float16* hb[2] = {hbuf0, hbuf1};
  for(int t=0;t<T_;++t){
    k_step<<<dim3(32,2),256,0,stream>>>(t,
        (const half8*)hb[t&1], (half8*)hb[(t+1)&1],
        (const half8*)Ufrag,
        PT, PT + (size_t)DV*H_, PT + (size_t)2*DV*H_, xT);
  }
  // final h is in hbuf0 (t=255 writes buffer (255+1)&1 = 0)
  k_unfrag<<<512,256,0,stream>>>(hbuf0, hlin);
  k_out_gemm<<<32,256,0,stream>>>(hlin, Wph, bp, yT);
  k_logsoftmax<<<128,256,0,stream>>>(yT, out);
}